// Round 2
// baseline (86.019 us; speedup 1.0000x reference)
//
#include <hip/hip_runtime.h>

// Input order (setup_inputs): 0:x0 1:x1_src 2:w0 3:b0 4:w1 5:b1
//                             6:wm 7:bm 8:wo 9:bo 10:wl 11:bl
// All float32. Output: [8,3,32,32] float32 (24576 elements).
//
// Algebraic collapse: softmax over a size-1 axis == 1.0 identically, so the
// conv/attention pipeline reduces to:
//   m[c]       = bm[c] + sum_k wm[c,k]
//   v[o]       = bo[o] + sum_c wo[o,c] * m[c]            (o in 0..2)
//   out[b,o,p] = bl[o] + sum_c wl[o,c] * (v[c] + x1_src[b,c,p])
//
// Single fused kernel: every block redundantly computes v (256 KB wm read,
// coalesced, L2-absorbed across blocks), then handles its 256 pixels.
// No workspace, no inter-kernel dependency, one launch (launch-overhead floor).

#define C 256
#define HW 1024

__global__ __launch_bounds__(256) void
fused_kernel(const float* __restrict__ x1s, const float* __restrict__ wm,
             const float* __restrict__ bm, const float* __restrict__ wo,
             const float* __restrict__ bo, const float* __restrict__ wl,
             const float* __restrict__ bl, float* __restrict__ out) {
    const int t = threadIdx.x;

    // v[o] = bo[o] + sum_c wo[o,c]*(bm[c] + sum_k wm[c,k])
    // Reorder: thread t owns column k=t of wm; row index c is wave-uniform,
    // so wo[*,c] are scalar loads and wm reads are fully coalesced.
    float a0 = 0.f, a1 = 0.f, a2 = 0.f;
#pragma unroll 8
    for (int c = 0; c < C; ++c) {
        const float x = wm[c * C + t];
        a0 = fmaf(wo[c], x, a0);
        a1 = fmaf(wo[C + c], x, a1);
        a2 = fmaf(wo[2 * C + c], x, a2);
    }
    // bm term: c == t for this thread's contribution.
    {
        const float bmt = bm[t];
        a0 = fmaf(wo[t], bmt, a0);
        a1 = fmaf(wo[C + t], bmt, a1);
        a2 = fmaf(wo[2 * C + t], bmt, a2);
    }

    // Reduce (a0,a1,a2) across the block: wave64 butterfly, then LDS.
    for (int off = 32; off > 0; off >>= 1) {
        a0 += __shfl_down(a0, off);
        a1 += __shfl_down(a1, off);
        a2 += __shfl_down(a2, off);
    }
    __shared__ float sw[3][4];
    __shared__ float sv[3];
    const int wave = t >> 6, lane = t & 63;
    if (lane == 0) { sw[0][wave] = a0; sw[1][wave] = a1; sw[2][wave] = a2; }
    __syncthreads();
    if (t < 3) sv[t] = bo[t] + sw[t][0] + sw[t][1] + sw[t][2] + sw[t][3];
    __syncthreads();
    const float v0 = sv[0], v1 = sv[1], v2 = sv[2];

    // Final 3x3 channel mix per pixel.
    const float l00 = wl[0], l01 = wl[1], l02 = wl[2];
    const float l10 = wl[3], l11 = wl[4], l12 = wl[5];
    const float l20 = wl[6], l21 = wl[7], l22 = wl[8];
    const float c0 = bl[0], c1 = bl[1], c2 = bl[2];

    const int idx = blockIdx.x * 256 + t;   // 0..8191 = B*HW
    const int b = idx >> 10;
    const int p = idx & (HW - 1);

    const float* xb = x1s + (size_t)b * 3 * HW;
    const float t0 = v0 + xb[p];
    const float t1 = v1 + xb[HW + p];
    const float t2 = v2 + xb[2 * HW + p];

    float* ob = out + (size_t)b * 3 * HW;
    ob[p]          = c0 + fmaf(l00, t0, fmaf(l01, t1, l02 * t2));
    ob[HW + p]     = c1 + fmaf(l10, t0, fmaf(l11, t1, l12 * t2));
    ob[2 * HW + p] = c2 + fmaf(l20, t0, fmaf(l21, t1, l22 * t2));
}

extern "C" void kernel_launch(void* const* d_in, const int* in_sizes, int n_in,
                              void* d_out, int out_size, void* d_ws, size_t ws_size,
                              hipStream_t stream) {
    const float* x1_src = (const float*)d_in[1];
    const float* wm = (const float*)d_in[6];
    const float* bm = (const float*)d_in[7];
    const float* wo = (const float*)d_in[8];
    const float* bo = (const float*)d_in[9];
    const float* wl = (const float*)d_in[10];
    const float* bl = (const float*)d_in[11];
    float* out = (float*)d_out;

    fused_kernel<<<32, 256, 0, stream>>>(x1_src, wm, bm, wo, bo, wl, bl, out);
}

// Round 3
// 81.313 us; speedup vs baseline: 1.0579x; 1.0579x over previous
//
#include <hip/hip_runtime.h>

// Input order (setup_inputs): 0:x0 1:x1_src 2:w0 3:b0 4:w1 5:b1
//                             6:wm 7:bm 8:wo 9:bo 10:wl 11:bl
// All float32. Output: [8,3,32,32] float32 (24576 elements).
//
// Algebraic collapse: softmax over a size-1 axis == 1.0 identically, so the
// conv/attention pipeline reduces to:
//   m[c]       = bm[c] + sum_k wm[c,k]
//   v[o]       = bo[o] + sum_c wo[o,c] * m[c]            (o in 0..2)
//   out[b,o,p] = bl[o] + sum_c wl[o,c] * (v[c] + x1_src[b,c,p])
//
// Single kernel, 32 blocks. Each block redundantly computes v by scanning the
// full 256 KB wm with float4 loads (64 iters, unroll 16 -> ~16 loads in
// flight, latency-bound cost ~1 us; L2 absorbs the 8 MB of cross-block
// redundancy). Row index per float4 is wave-uniform, so wo factors are LDS
// broadcasts. Then each block does the 3x3 channel mix for its 256 pixels.

#define C 256
#define HW 1024

__global__ __launch_bounds__(256) void
fused_kernel(const float* __restrict__ x1s, const float* __restrict__ wm,
             const float* __restrict__ bm, const float* __restrict__ wo,
             const float* __restrict__ bo, const float* __restrict__ wl,
             const float* __restrict__ bl, float* __restrict__ out) {
    const int t = threadIdx.x;
    const int wave = t >> 6, lane = t & 63;

    // Preload wo rows into LDS (3 KB) for broadcast reads in the hot loop.
    __shared__ float swo[3][C];
    swo[0][t] = wo[t];
    swo[1][t] = wo[C + t];
    swo[2][t] = wo[2 * C + t];
    __syncthreads();

    // bm contribution: thread t covers c == t.
    const float bmt = bm[t];
    float a0 = swo[0][t] * bmt;
    float a1 = swo[1][t] * bmt;
    float a2 = swo[2][t] * bmt;

    // wm rowsum contribution. float4 f-index = i*256 + t; row c = i*4 + wave
    // (wave-uniform -> swo reads are broadcasts). Fully coalesced 1 KB/instr.
    const float4* __restrict__ wmv = (const float4*)wm;
#pragma unroll 16
    for (int i = 0; i < 64; ++i) {
        const float4 x = wmv[i * 256 + t];
        const float s = (x.x + x.y) + (x.z + x.w);
        const int c = i * 4 + wave;
        a0 = fmaf(swo[0][c], s, a0);
        a1 = fmaf(swo[1][c], s, a1);
        a2 = fmaf(swo[2][c], s, a2);
    }

    // Block-wide reduction: wave64 butterfly, then cross-wave via LDS.
    for (int off = 32; off > 0; off >>= 1) {
        a0 += __shfl_down(a0, off);
        a1 += __shfl_down(a1, off);
        a2 += __shfl_down(a2, off);
    }
    __shared__ float sw[3][4];
    __shared__ float sv[3];
    if (lane == 0) { sw[0][wave] = a0; sw[1][wave] = a1; sw[2][wave] = a2; }
    __syncthreads();
    if (t < 3) sv[t] = bo[t] + (sw[t][0] + sw[t][1]) + (sw[t][2] + sw[t][3]);
    __syncthreads();
    const float v0 = sv[0], v1 = sv[1], v2 = sv[2];

    // Final 3x3 channel mix per pixel.
    const float l00 = wl[0], l01 = wl[1], l02 = wl[2];
    const float l10 = wl[3], l11 = wl[4], l12 = wl[5];
    const float l20 = wl[6], l21 = wl[7], l22 = wl[8];
    const float c0 = bl[0], c1 = bl[1], c2 = bl[2];

    const int idx = blockIdx.x * 256 + t;   // 0..8191 = B*HW pixels
    const int b = idx >> 10;
    const int p = idx & (HW - 1);

    const float* xb = x1s + (size_t)b * 3 * HW;
    const float t0 = v0 + xb[p];
    const float t1 = v1 + xb[HW + p];
    const float t2 = v2 + xb[2 * HW + p];

    float* ob = out + (size_t)b * 3 * HW;
    ob[p]          = c0 + fmaf(l00, t0, fmaf(l01, t1, l02 * t2));
    ob[HW + p]     = c1 + fmaf(l10, t0, fmaf(l11, t1, l12 * t2));
    ob[2 * HW + p] = c2 + fmaf(l20, t0, fmaf(l21, t1, l22 * t2));
}

extern "C" void kernel_launch(void* const* d_in, const int* in_sizes, int n_in,
                              void* d_out, int out_size, void* d_ws, size_t ws_size,
                              hipStream_t stream) {
    const float* x1_src = (const float*)d_in[1];
    const float* wm = (const float*)d_in[6];
    const float* bm = (const float*)d_in[7];
    const float* wo = (const float*)d_in[8];
    const float* bo = (const float*)d_in[9];
    const float* wl = (const float*)d_in[10];
    const float* bl = (const float*)d_in[11];
    float* out = (float*)d_out;

    fused_kernel<<<32, 256, 0, stream>>>(x1_src, wm, bm, wo, bo, wl, bl, out);
}